// Round 5
// baseline (48128.021 us; speedup 1.0000x reference)
//
#include <hip/hip_runtime.h>
#include <hip/hip_fp16.h>

#define NTRAJ   256
#define NTP     512
#define NSTEPS  511
#define LATENT  256
#define INPUT   128
#define DEC_OUT 128

#define OUT_VOL ((size_t)NTRAJ * LATENT)                              // 65536
#define OUT_DTS (OUT_VOL + (size_t)NTRAJ * NSTEPS * DEC_OUT)          // 16809984

// Pair-interleaved fp16 weight workspace (offsets in uint32 = half2 units).
// Layout per matrix [K][C]: ws[kp*C + c] = half2(W[2kp][c], W[2kp+1][c]).
#define WU_UG1  0
#define WU_UG2  49152
#define WU_UGT1 81920
#define WU_UGT2 131072
#define WU_RG1  163840
#define WU_RG2  212992
#define WU_NS1  245760
#define WU_NS2  294912
#define WU_DK1  327680
#define WU_DEC  360448
#define WU_TOT  376832

typedef _Float16 h2_t __attribute__((ext_vector_type(2)));
union U32H2 { unsigned int u; h2_t h; };

__device__ __forceinline__ float dot2f(unsigned int wu, unsigned int xu, float acc) {
#if defined(__has_builtin) && __has_builtin(__builtin_amdgcn_fdot2)
    U32H2 a, b; a.u = wu; b.u = xu;
    return __builtin_amdgcn_fdot2(a.h, b.h, acc, false);
#else
    U32H2 a, b; a.u = wu; b.u = xu;
    return acc + (float)a.h.x * (float)b.h.x + (float)a.h.y * (float)b.h.y;
#endif
}

__device__ __forceinline__ float wred(float v) {
    #pragma unroll
    for (int off = 32; off; off >>= 1) v += __shfl_down(v, off, 64);
    return v;
}
__device__ __forceinline__ float fast_sigmoid(float x) { return 1.0f / (1.0f + __expf(-x)); }
__device__ __forceinline__ float fast_tanh(float x) {
    float e = __expf(2.0f * x);
    return 1.0f - 2.0f / (e + 1.0f);
}
// Pack (v_even, v_odd) from adjacent lanes into one half2; only even lanes
// hold the correct result and write. Must be called by full waves.
__device__ __forceinline__ unsigned int packpair(float v) {
    float vn = __shfl_xor(v, 1, 64);
    U32H2 r; r.h.x = (_Float16)v; r.h.y = (_Float16)vn;
    return r.u;
}
// Pack two in-lane floats into one half2 word (no shuffle needed).
__device__ __forceinline__ unsigned int pk2(float a, float b) {
    U32H2 r; r.h.x = (_Float16)a; r.h.y = (_Float16)b; return r.u;
}
// Butterfly-add a float4 across lanes at xor-distance m.
__device__ __forceinline__ float4 bfly4(float4 v, int m) {
    v.x += __shfl_xor(v.x, m, 64);
    v.y += __shfl_xor(v.y, m, 64);
    v.z += __shfl_xor(v.z, m, 64);
    v.w += __shfl_xor(v.w, m, 64);
    return v;
}

// ---- weight prep: fp32 -> k-pair-interleaved half2 ----
extern "C" __global__ void __launch_bounds__(256)
convert_w(const float* __restrict__ ug_w1, const float* __restrict__ ug_w2,
          const float* __restrict__ ugt_w1, const float* __restrict__ ugt_w2,
          const float* __restrict__ rg_w1, const float* __restrict__ rg_w2,
          const float* __restrict__ ns_w1, const float* __restrict__ ns_w2,
          const float* __restrict__ dk_w1, const float* __restrict__ dec_w,
          unsigned int* __restrict__ ws)
{
    const int i = blockIdx.x * 256 + threadIdx.x;
    const float* s; int o; int cbits;
    if      (i < WU_UG2)  { s = ug_w1;  o = i;           cbits = 8; }
    else if (i < WU_UGT1) { s = ug_w2;  o = i - WU_UG2;  cbits = 8; }
    else if (i < WU_UGT2) { s = ugt_w1; o = i - WU_UGT1; cbits = 8; }
    else if (i < WU_RG1)  { s = ugt_w2; o = i - WU_UGT2; cbits = 8; }
    else if (i < WU_RG2)  { s = rg_w1;  o = i - WU_RG1;  cbits = 8; }
    else if (i < WU_NS1)  { s = rg_w2;  o = i - WU_RG2;  cbits = 8; }
    else if (i < WU_NS2)  { s = ns_w1;  o = i - WU_NS1;  cbits = 8; }
    else if (i < WU_DK1)  { s = ns_w2;  o = i - WU_NS2;  cbits = 8; }
    else if (i < WU_DEC)  { s = dk_w1;  o = i - WU_DK1;  cbits = 8; }
    else                  { s = dec_w;  o = i - WU_DEC;  cbits = 7; }
    const int C  = 1 << cbits;
    const int kp = o >> cbits;
    const int c  = o & (C - 1);
    const float v0 = s[(2 * kp) * C + c];
    const float v1 = s[(2 * kp + 1) * C + c];
    const unsigned int h0 = __half_as_ushort(__float2half(v0));
    const unsigned int h1 = __half_as_ushort(__float2half(v1));
    ws[i] = h0 | (h1 << 16);
}

// Macro hygiene: no parameter named x/y/z/w (body does member access).
// acc.{x,y,z,w} are 4 adjacent output columns sharing one x half2.
#define DOT1(acc, wv, xv) { \
    acc.x = dot2f((wv).x, (xv), acc.x); acc.y = dot2f((wv).y, (xv), acc.y); \
    acc.z = dot2f((wv).z, (xv), acc.z); acc.w = dot2f((wv).w, (xv), acc.w); }

// ---- chunked-prefetch helpers (all statically indexed; no dynamic arrays) ----
// Weight chunk: 4 iters (kp = sl + 8*i, i = 4*ch..4*ch+3), cols c0, stride 256.
#define WLD1(Aq, Pa, ch) { \
    _Pragma("unroll") \
    for (int j_ = 0; j_ < 4; ++j_) { \
        const int kp_ = sl + (((ch) << 2) + j_) * 8; \
        Aq[j_] = *(const uint4*)((Pa) + (size_t)kp_ * 256 + c0); } }

#define WLD3(Aq, Bq, Cq, Pa, Pb, Pc, ch) { \
    _Pragma("unroll") \
    for (int j_ = 0; j_ < 4; ++j_) { \
        const int kp_ = sl + (((ch) << 2) + j_) * 8; \
        Aq[j_] = *(const uint4*)((Pa) + (size_t)kp_ * 256 + c0); \
        Bq[j_] = *(const uint4*)((Pb) + (size_t)kp_ * 256 + c0); \
        Cq[j_] = *(const uint4*)((Pc) + (size_t)kp_ * 256 + c0); } }

// x chunk from one LDS source.
#define XRD(xq, S, ch) { \
    _Pragma("unroll") \
    for (int j_ = 0; j_ < 4; ++j_) \
        xq[j_] = (S)[sl + (((ch) << 2) + j_) * 8]; }

#define XRD3(xqa, xqb, xqc, ch) { \
    _Pragma("unroll") \
    for (int j_ = 0; j_ < 4; ++j_) { \
        const int kp_ = sl + (((ch) << 2) + j_) * 8; \
        xqa[j_] = s_a_h[kp_]; xqb[j_] = s_b_h[kp_]; xqc[j_] = s_c_h[kp_]; } }

#define DOTC1(acc, Aq, xq) { \
    _Pragma("unroll") \
    for (int j_ = 0; j_ < 4; ++j_) DOT1(acc, Aq[j_], xq[j_]); }

#define DOTC3(Aq, Bq, Cq, xq) { \
    _Pragma("unroll") \
    for (int j_ = 0; j_ < 4; ++j_) { \
        DOT1(aA, Aq[j_], xq[j_]); DOT1(aB, Bq[j_], xq[j_]); DOT1(aC, Cq[j_], xq[j_]); } }

#define DOTG2(Aq, Bq, Cq, xqa, xqb, xqc) { \
    _Pragma("unroll") \
    for (int j_ = 0; j_ < 4; ++j_) { \
        DOT1(aA, Aq[j_], xqa[j_]); DOT1(aB, Bq[j_], xqb[j_]); DOT1(aC, Cq[j_], xqc[j_]); } }

// dec GEMV: kp = sld + 16*i, cols c0d, stride 128.
#define WLDD(Dq, ch) { \
    _Pragma("unroll") \
    for (int j_ = 0; j_ < 4; ++j_) { \
        const int kp_ = sld + (((ch) << 2) + j_) * 16; \
        Dq[j_] = *(const uint4*)(DECW + (size_t)kp_ * 128 + c0d); } }

#define XRDD(xq, ch) { \
    _Pragma("unroll") \
    for (int j_ = 0; j_ < 4; ++j_) \
        xq[j_] = s_v_h[sld + (((ch) << 2) + j_) * 16]; }

extern "C" __global__ void __launch_bounds__(512, 2)
rnn_decay_kernel5(const float* __restrict__ data, const float* __restrict__ ts,
                  const float* __restrict__ ug_b1, const float* __restrict__ ug_b2,
                  const float* __restrict__ ugt_b1, const float* __restrict__ ugt_b2,
                  const float* __restrict__ rg_b1, const float* __restrict__ rg_b2,
                  const float* __restrict__ ns_b1, const float* __restrict__ ns_b2,
                  const float* __restrict__ dk_b1, const float* __restrict__ dk_w2,
                  const float* __restrict__ dk_b2, const float* __restrict__ dec_b,
                  const unsigned int* __restrict__ wsu, float* __restrict__ out)
{
    // Column-split: wave w owns cols [32w,32w+32); lane owns 4 adjacent cols;
    // 8 kp-slices per wave reduced via shfl_xor. 6 barriers/step.
    // This revision: explicit chunked weight prefetch (deep MLP per wave).
    __shared__ __align__(16) unsigned int s_in_h[192];  // [ydec(128)|xh(64)] half2
    __shared__ __align__(16) unsigned int s_ns_h[192];  // [y*r (128)|xh(64)] half2
    __shared__ __align__(16) unsigned int s_y_h[128];   // y half2 (dk1 src)
    __shared__ __align__(16) unsigned int s_a_h[128];   // h / ns-h half2
    __shared__ __align__(16) unsigned int s_b_h[128];   // ht half2
    __shared__ __align__(16) unsigned int s_c_h[128];   // hr half2
    __shared__ __align__(16) unsigned int s_v_h[128];   // vol half2
    __shared__ float s_red[12];                         // [0..3] mask, [4..11] dk

    const int tid  = threadIdx.x;
    const int w    = tid >> 6;
    const int lane = tid & 63;
    const int c    = tid & 255;
    const int sl   = lane >> 3;                 // kp slice 0..7
    const int g    = lane & 7;                  // col group 0..7
    const int c0   = (w << 5) + (g << 2);       // first of 4 owned cols (0..252)
    const int h2b  = c0 >> 1;                   // half2-unit base for packs
    const int sld  = lane >> 2;                 // dec: kp slice 0..15
    const int c0d  = (w << 4) + ((lane & 3) << 2);  // dec: first of 4 cols (0..124)
    const int traj = blockIdx.x;

    const unsigned int* UG1  = wsu + WU_UG1;  const unsigned int* UG2  = wsu + WU_UG2;
    const unsigned int* UGT1 = wsu + WU_UGT1; const unsigned int* UGT2 = wsu + WU_UGT2;
    const unsigned int* RG1  = wsu + WU_RG1;  const unsigned int* RG2  = wsu + WU_RG2;
    const unsigned int* NS1  = wsu + WU_NS1;  const unsigned int* NS2  = wsu + WU_NS2;
    const unsigned int* DK1  = wsu + WU_DK1;  const unsigned int* DECW = wsu + WU_DEC;

    const float* dbase = data + (size_t)traj * NTP * (2 * INPUT);
    const float* tbase = ts + (size_t)traj * NTP;
    float* vol_out = out + OUT_VOL + (size_t)traj * NSTEPS * DEC_OUT;
    float* dts_out = out + OUT_DTS + (size_t)traj * NSTEPS;

    if (tid < 256)
        for (int t0 = c; t0 < NSTEPS; t0 += 256)
            dts_out[t0] = tbase[t0 + 1] - tbase[t0];

    const float dkb2s = dk_b2[0];

    float4 y4  = make_float4(0.f, 0.f, 0.f, 0.f);   // GRU state: owned cols
    float4 yt4 = y4;

    for (int t = -1; t < NSTEPS; ++t) {
        const bool first = (t < 0);

        // ================= phase X: x-stage + mask + dk1 dot =================
        float dt_t = 0.f;
        if (!first) dt_t = tbase[t + 1] - tbase[t];
        float xval = 0.f;
        if (tid < 256)
            xval = first ? dbase[c] : dbase[(size_t)(t + 1) * 256 + c];

        if (!first) {
            // dk1: K=256 → 4 chunks; load all (16 in flight), then dot.
            uint4 k0[4], k1[4], k2[4], k3[4];
            unsigned q0[4], q1[4], q2[4], q3[4];
            WLD1(k0, DK1, 0); XRD(q0, s_y_h, 0);
            WLD1(k1, DK1, 1); XRD(q1, s_y_h, 1);
            WLD1(k2, DK1, 2); XRD(q2, s_y_h, 2);
            WLD1(k3, DK1, 3); XRD(q3, s_y_h, 3);
            float4 aD = make_float4(0.f, 0.f, 0.f, 0.f);
            DOTC1(aD, k0, q0); DOTC1(aD, k1, q1);
            DOTC1(aD, k2, q2); DOTC1(aD, k3, q3);
            aD = bfly4(aD, 8); aD = bfly4(aD, 16); aD = bfly4(aD, 32);
            const float4 dkb1v = *(const float4*)(dk_b1 + c0);
            const float4 dkw2v = *(const float4*)(dk_w2 + c0);
            float sdk = fmaxf(aD.x + dkb1v.x, 0.f) * dkw2v.x
                      + fmaxf(aD.y + dkb1v.y, 0.f) * dkw2v.y
                      + fmaxf(aD.z + dkb1v.z, 0.f) * dkw2v.z
                      + fmaxf(aD.w + dkb1v.w, 0.f) * dkw2v.w;
            sdk += __shfl_xor(sdk, 1, 64);
            sdk += __shfl_xor(sdk, 2, 64);
            sdk += __shfl_xor(sdk, 4, 64);
            if (lane == 0) s_red[4 + w] = sdk;
        }
        if (tid < 256) {
            float mv = (c >= 128) ? xval : 0.f;
            mv = wred(mv);
            if (lane == 0) s_red[w] = mv;               // w in 0..3 here
            if (c < 128) {
                const unsigned int px = packpair(xval);
                if (!(lane & 1)) { s_in_h[128 + (c >> 1)] = px; s_ns_h[128 + (c >> 1)] = px; }
            }
            if (first && !(lane & 1)) s_in_h[c >> 1] = 0u;   // ydec = 0
        }
        __syncthreads();                                               // A

        // ================= phase Y: decay scalar + ydec/vol pack =============
        const bool maskv = (s_red[0] + s_red[1] + s_red[2] + s_red[3]) > 0.f;
        float4 ydec4 = make_float4(0.f, 0.f, 0.f, 0.f);
        if (!first) {
            const float decay = fmaxf(s_red[4] + s_red[5] + s_red[6] + s_red[7]
                                    + s_red[8] + s_red[9] + s_red[10] + s_red[11]
                                    + dkb2s, 0.f);
            const float ef = __expf(-decay * dt_t);
            const float eh = __expf(-0.5f * decay * dt_t);
            float4 vol4;
            ydec4.x = yt4.x + (y4.x - yt4.x) * ef;
            ydec4.y = yt4.y + (y4.y - yt4.y) * ef;
            ydec4.z = yt4.z + (y4.z - yt4.z) * ef;
            ydec4.w = yt4.w + (y4.w - yt4.w) * ef;
            vol4.x = 0.5f * (y4.x + yt4.x + (y4.x - yt4.x) * eh);
            vol4.y = 0.5f * (y4.y + yt4.y + (y4.y - yt4.y) * eh);
            vol4.z = 0.5f * (y4.z + yt4.z + (y4.z - yt4.z) * eh);
            vol4.w = 0.5f * (y4.w + yt4.w + (y4.w - yt4.w) * eh);
            if (!sl) {
                uint2 pd; pd.x = pk2(ydec4.x, ydec4.y); pd.y = pk2(ydec4.z, ydec4.w);
                uint2 pv; pv.x = pk2(vol4.x, vol4.y);   pv.y = pk2(vol4.z, vol4.w);
                *(uint2*)(s_in_h + h2b) = pd;
                *(uint2*)(s_v_h + h2b)  = pv;
            }
        }
        __syncthreads();                                               // B

        // ================= phase G1: dec + ug1/ugt1/rg1 (pipelined) ==========
        {
            // dec loads first (oldest in flight → ready soonest) …
            uint4 d0[4], d1[4]; unsigned xd0[4], xd1[4];
            if (!first) { WLDD(d0, 0); WLDD(d1, 1); XRDD(xd0, 0); XRDD(xd1, 1); }
            // … then G1 chunk0/1 loads …
            uint4 A0[4], B0[4], C0[4], A1[4], B1[4], C1[4];
            unsigned xg0[4], xg1[4];
            WLD3(A0, B0, C0, UG1, UGT1, RG1, 0); XRD(xg0, s_in_h, 0);
            WLD3(A1, B1, C1, UG1, UGT1, RG1, 1); XRD(xg1, s_in_h, 1);
            // … dec dots run under G1 load latency.
            if (!first) {
                float4 aE = make_float4(0.f, 0.f, 0.f, 0.f);
                DOTC1(aE, d0, xd0); DOTC1(aE, d1, xd1);
                aE = bfly4(aE, 4); aE = bfly4(aE, 8);
                aE = bfly4(aE, 16); aE = bfly4(aE, 32);
                if (sld == 0) {
                    const float4 decbv = *(const float4*)(dec_b + c0d);
                    float4 o;
                    o.x = aE.x + decbv.x; o.y = aE.y + decbv.y;
                    o.z = aE.z + decbv.z; o.w = aE.w + decbv.w;
                    *(float4*)(vol_out + (size_t)t * DEC_OUT + c0d) = o;
                }
            }
            float4 aA = make_float4(0.f, 0.f, 0.f, 0.f), aB = aA, aC = aA;
            DOTC3(A0, B0, C0, xg0);
            WLD3(A0, B0, C0, UG1, UGT1, RG1, 2); XRD(xg0, s_in_h, 2);
            DOTC3(A1, B1, C1, xg1);
            WLD3(A1, B1, C1, UG1, UGT1, RG1, 3); XRD(xg1, s_in_h, 3);
            DOTC3(A0, B0, C0, xg0);
            WLD3(A0, B0, C0, UG1, UGT1, RG1, 4); XRD(xg0, s_in_h, 4);
            DOTC3(A1, B1, C1, xg1);
            WLD3(A1, B1, C1, UG1, UGT1, RG1, 5); XRD(xg1, s_in_h, 5);
            DOTC3(A0, B0, C0, xg0);
            DOTC3(A1, B1, C1, xg1);
            aA = bfly4(aA, 8); aA = bfly4(aA, 16); aA = bfly4(aA, 32);
            aB = bfly4(aB, 8); aB = bfly4(aB, 16); aB = bfly4(aB, 32);
            aC = bfly4(aC, 8); aC = bfly4(aC, 16); aC = bfly4(aC, 32);
            if (!sl) {
                const float4 ugb1v  = *(const float4*)(ug_b1  + c0);
                const float4 ugtb1v = *(const float4*)(ugt_b1 + c0);
                const float4 rgb1v  = *(const float4*)(rg_b1  + c0);
                uint2 pa, pb, pc;
                pa.x = pk2(fast_tanh(aA.x + ugb1v.x),  fast_tanh(aA.y + ugb1v.y));
                pa.y = pk2(fast_tanh(aA.z + ugb1v.z),  fast_tanh(aA.w + ugb1v.w));
                pb.x = pk2(fast_tanh(aB.x + ugtb1v.x), fast_tanh(aB.y + ugtb1v.y));
                pb.y = pk2(fast_tanh(aB.z + ugtb1v.z), fast_tanh(aB.w + ugtb1v.w));
                pc.x = pk2(fast_tanh(aC.x + rgb1v.x),  fast_tanh(aC.y + rgb1v.y));
                pc.y = pk2(fast_tanh(aC.z + rgb1v.z),  fast_tanh(aC.w + rgb1v.w));
                *(uint2*)(s_a_h + h2b) = pa;
                *(uint2*)(s_b_h + h2b) = pb;
                *(uint2*)(s_c_h + h2b) = pc;
            }
        }
        __syncthreads();                                               // C

        // ================= phase G2: ug2/ugt2/rg2 → u, ut, r (pipelined) =====
        float4 u4, ut4;
        {
            uint4 A0[4], B0[4], C0[4], A1[4], B1[4], C1[4];
            unsigned xa0[4], xb0[4], xc0[4], xa1[4], xb1[4], xc1[4];
            WLD3(A0, B0, C0, UG2, UGT2, RG2, 0); XRD3(xa0, xb0, xc0, 0);
            WLD3(A1, B1, C1, UG2, UGT2, RG2, 1); XRD3(xa1, xb1, xc1, 1);
            float4 aA = make_float4(0.f, 0.f, 0.f, 0.f), aB = aA, aC = aA;
            DOTG2(A0, B0, C0, xa0, xb0, xc0);
            WLD3(A0, B0, C0, UG2, UGT2, RG2, 2); XRD3(xa0, xb0, xc0, 2);
            DOTG2(A1, B1, C1, xa1, xb1, xc1);
            WLD3(A1, B1, C1, UG2, UGT2, RG2, 3); XRD3(xa1, xb1, xc1, 3);
            DOTG2(A0, B0, C0, xa0, xb0, xc0);
            DOTG2(A1, B1, C1, xa1, xb1, xc1);
            aA = bfly4(aA, 8); aA = bfly4(aA, 16); aA = bfly4(aA, 32);
            aB = bfly4(aB, 8); aB = bfly4(aB, 16); aB = bfly4(aB, 32);
            aC = bfly4(aC, 8); aC = bfly4(aC, 16); aC = bfly4(aC, 32);
            const float4 ugb2v  = *(const float4*)(ug_b2  + c0);
            const float4 ugtb2v = *(const float4*)(ugt_b2 + c0);
            const float4 rgb2v  = *(const float4*)(rg_b2  + c0);
            u4.x  = fast_sigmoid(aA.x + ugb2v.x);  u4.y  = fast_sigmoid(aA.y + ugb2v.y);
            u4.z  = fast_sigmoid(aA.z + ugb2v.z);  u4.w  = fast_sigmoid(aA.w + ugb2v.w);
            ut4.x = fast_sigmoid(aB.x + ugtb2v.x); ut4.y = fast_sigmoid(aB.y + ugtb2v.y);
            ut4.z = fast_sigmoid(aB.z + ugtb2v.z); ut4.w = fast_sigmoid(aB.w + ugtb2v.w);
            const float rx = fast_sigmoid(aC.x + rgb2v.x);
            const float ry = fast_sigmoid(aC.y + rgb2v.y);
            const float rz = fast_sigmoid(aC.z + rgb2v.z);
            const float rw = fast_sigmoid(aC.w + rgb2v.w);
            if (!sl) {
                uint2 pn;
                pn.x = pk2(ydec4.x * rx, ydec4.y * ry);
                pn.y = pk2(ydec4.z * rz, ydec4.w * rw);
                *(uint2*)(s_ns_h + h2b) = pn;      // first step: ydec=0 → 0 ✓
            }
        }
        __syncthreads();                                               // D

        // ================= phase N1: ns1 (24 iters, double-buffered) =========
        {
            uint4 n0[4], n1[4]; unsigned q0[4], q1[4];
            WLD1(n0, NS1, 0); XRD(q0, s_ns_h, 0);
            WLD1(n1, NS1, 1); XRD(q1, s_ns_h, 1);
            float4 aA = make_float4(0.f, 0.f, 0.f, 0.f);
            DOTC1(aA, n0, q0);
            WLD1(n0, NS1, 2); XRD(q0, s_ns_h, 2);
            DOTC1(aA, n1, q1);
            WLD1(n1, NS1, 3); XRD(q1, s_ns_h, 3);
            DOTC1(aA, n0, q0);
            WLD1(n0, NS1, 4); XRD(q0, s_ns_h, 4);
            DOTC1(aA, n1, q1);
            WLD1(n1, NS1, 5); XRD(q1, s_ns_h, 5);
            DOTC1(aA, n0, q0);
            DOTC1(aA, n1, q1);
            aA = bfly4(aA, 8); aA = bfly4(aA, 16); aA = bfly4(aA, 32);
            if (!sl) {
                const float4 nsb1v = *(const float4*)(ns_b1 + c0);
                uint2 ph;
                ph.x = pk2(fast_tanh(aA.x + nsb1v.x), fast_tanh(aA.y + nsb1v.y));
                ph.y = pk2(fast_tanh(aA.z + nsb1v.z), fast_tanh(aA.w + nsb1v.w));
                *(uint2*)(s_a_h + h2b) = ph;       // reuse s_a_h (G2 done)
            }
        }
        __syncthreads();                                               // E

        // ================= phase N2: ns2 + state update (load-all) ===========
        {
            uint4 n0[4], n1[4], n2[4], n3[4];
            unsigned q0[4], q1[4], q2[4], q3[4];
            WLD1(n0, NS2, 0); XRD(q0, s_a_h, 0);
            WLD1(n1, NS2, 1); XRD(q1, s_a_h, 1);
            WLD1(n2, NS2, 2); XRD(q2, s_a_h, 2);
            WLD1(n3, NS2, 3); XRD(q3, s_a_h, 3);
            float4 aA = make_float4(0.f, 0.f, 0.f, 0.f);
            DOTC1(aA, n0, q0); DOTC1(aA, n1, q1);
            DOTC1(aA, n2, q2); DOTC1(aA, n3, q3);
            aA = bfly4(aA, 8); aA = bfly4(aA, 16); aA = bfly4(aA, 32);
            const float4 nsb2v = *(const float4*)(ns_b2 + c0);
            const float nx = aA.x + nsb2v.x, ny_ = aA.y + nsb2v.y;
            const float nz = aA.z + nsb2v.z, nw = aA.w + nsb2v.w;
            const float yx = (1.f - u4.x) * nx  + u4.x * ydec4.x;
            const float yy = (1.f - u4.y) * ny_ + u4.y * ydec4.y;
            const float yz = (1.f - u4.z) * nz  + u4.z * ydec4.z;
            const float yw = (1.f - u4.w) * nw  + u4.w * ydec4.w;
            const float tx = (1.f - ut4.x) * nx  + ut4.x * yt4.x;
            const float ty = (1.f - ut4.y) * ny_ + ut4.y * yt4.y;
            const float tz = (1.f - ut4.z) * nz  + ut4.z * yt4.z;
            const float tw = (1.f - ut4.w) * nw  + ut4.w * yt4.w;
            y4.x  = maskv ? yx : ydec4.x;  y4.y  = maskv ? yy : ydec4.y;
            y4.z  = maskv ? yz : ydec4.z;  y4.w  = maskv ? yw : ydec4.w;
            yt4.x = maskv ? tx : yt4.x;    yt4.y = maskv ? ty : yt4.y;
            yt4.z = maskv ? tz : yt4.z;    yt4.w = maskv ? tw : yt4.w;
            if (!sl) {
                uint2 py;
                py.x = pk2(y4.x, y4.y); py.y = pk2(y4.z, y4.w);
                *(uint2*)(s_y_h + h2b) = py;
            }
        }
        __syncthreads();                                               // F
    }

    if (!sl)
        *(float4*)(out + (size_t)traj * 256 + c0) = y4;
}

extern "C" void kernel_launch(void* const* d_in, const int* in_sizes, int n_in,
                              void* d_out, int out_size, void* d_ws, size_t ws_size,
                              hipStream_t stream) {
    const float* data   = (const float*)d_in[0];
    const float* ts     = (const float*)d_in[1];
    const float* ug_w1  = (const float*)d_in[2];
    const float* ug_b1  = (const float*)d_in[3];
    const float* ug_w2  = (const float*)d_in[4];
    const float* ug_b2  = (const float*)d_in[5];
    const float* ugt_w1 = (const float*)d_in[6];
    const float* ugt_b1 = (const float*)d_in[7];
    const float* ugt_w2 = (const float*)d_in[8];
    const float* ugt_b2 = (const float*)d_in[9];
    const float* rg_w1  = (const float*)d_in[10];
    const float* rg_b1  = (const float*)d_in[11];
    const float* rg_w2  = (const float*)d_in[12];
    const float* rg_b2  = (const float*)d_in[13];
    // d_in[14..17] = rgt_* : unused by the reference
    const float* ns_w1  = (const float*)d_in[18];
    const float* ns_b1  = (const float*)d_in[19];
    const float* ns_w2  = (const float*)d_in[20];
    const float* ns_b2  = (const float*)d_in[21];
    const float* dk_w1  = (const float*)d_in[22];
    const float* dk_b1  = (const float*)d_in[23];
    const float* dk_w2  = (const float*)d_in[24];
    const float* dk_b2  = (const float*)d_in[25];
    const float* dec_w  = (const float*)d_in[26];
    const float* dec_b  = (const float*)d_in[27];

    unsigned int* wsu = (unsigned int*)d_ws;

    convert_w<<<WU_TOT / 256, 256, 0, stream>>>(ug_w1, ug_w2, ugt_w1, ugt_w2,
                                                rg_w1, rg_w2, ns_w1, ns_w2,
                                                dk_w1, dec_w, wsu);

    rnn_decay_kernel5<<<NTRAJ, 512, 0, stream>>>(
        data, ts, ug_b1, ug_b2, ugt_b1, ugt_b2, rg_b1, rg_b2, ns_b1, ns_b2,
        dk_b1, dk_w2, dk_b2, dec_b, wsu, (float*)d_out);
}

// Round 6
// 10128.939 us; speedup vs baseline: 4.7515x; 4.7515x over previous
//
#include <hip/hip_runtime.h>
#include <hip/hip_fp16.h>

#define NTRAJ   256
#define NTP     512
#define NSTEPS  511
#define LATENT  256
#define INPUT   128
#define DEC_OUT 128

#define OUT_VOL ((size_t)NTRAJ * LATENT)                              // 65536
#define OUT_DTS (OUT_VOL + (size_t)NTRAJ * NSTEPS * DEC_OUT)          // 16809984

// Pair-interleaved fp16 weight workspace (offsets in uint32 = half2 units).
// Layout per matrix [K][C]: ws[kp*C + c] = half2(W[2kp][c], W[2kp+1][c]).
#define WU_UG1  0
#define WU_UG2  49152
#define WU_UGT1 81920
#define WU_UGT2 131072
#define WU_RG1  163840
#define WU_RG2  212992
#define WU_NS1  245760
#define WU_NS2  294912
#define WU_DK1  327680
#define WU_DEC  360448
#define WU_TOT  376832

typedef _Float16 h2_t __attribute__((ext_vector_type(2)));
union U32H2 { unsigned int u; h2_t h; };

__device__ __forceinline__ float dot2f(unsigned int wu, unsigned int xu, float acc) {
#if defined(__has_builtin) && __has_builtin(__builtin_amdgcn_fdot2)
    U32H2 a, b; a.u = wu; b.u = xu;
    return __builtin_amdgcn_fdot2(a.h, b.h, acc, false);
#else
    U32H2 a, b; a.u = wu; b.u = xu;
    return acc + (float)a.h.x * (float)b.h.x + (float)a.h.y * (float)b.h.y;
#endif
}

__device__ __forceinline__ float wred(float v) {
    #pragma unroll
    for (int off = 32; off; off >>= 1) v += __shfl_down(v, off, 64);
    return v;
}
__device__ __forceinline__ float fast_sigmoid(float x) { return 1.0f / (1.0f + __expf(-x)); }
__device__ __forceinline__ float fast_tanh(float x) {
    float e = __expf(2.0f * x);
    return 1.0f - 2.0f / (e + 1.0f);
}
// Pack (v_even, v_odd) from adjacent lanes into one half2; only even lanes
// hold the correct result and write. Must be called by full waves.
__device__ __forceinline__ unsigned int packpair(float v) {
    float vn = __shfl_xor(v, 1, 64);
    U32H2 r; r.h.x = (_Float16)v; r.h.y = (_Float16)vn;
    return r.u;
}
// Pack two in-lane floats into one half2 word (no shuffle needed).
__device__ __forceinline__ unsigned int pk2(float a, float b) {
    U32H2 r; r.h.x = (_Float16)a; r.h.y = (_Float16)b; return r.u;
}
// Butterfly-add a float4 across lanes at xor-distance m.
__device__ __forceinline__ float4 bfly4(float4 v, int m) {
    v.x += __shfl_xor(v.x, m, 64);
    v.y += __shfl_xor(v.y, m, 64);
    v.z += __shfl_xor(v.z, m, 64);
    v.w += __shfl_xor(v.w, m, 64);
    return v;
}

// ---- weight prep: fp32 -> k-pair-interleaved half2 ----
extern "C" __global__ void __launch_bounds__(256)
convert_w(const float* __restrict__ ug_w1, const float* __restrict__ ug_w2,
          const float* __restrict__ ugt_w1, const float* __restrict__ ugt_w2,
          const float* __restrict__ rg_w1, const float* __restrict__ rg_w2,
          const float* __restrict__ ns_w1, const float* __restrict__ ns_w2,
          const float* __restrict__ dk_w1, const float* __restrict__ dec_w,
          unsigned int* __restrict__ ws)
{
    const int i = blockIdx.x * 256 + threadIdx.x;
    const float* s; int o; int cbits;
    if      (i < WU_UG2)  { s = ug_w1;  o = i;           cbits = 8; }
    else if (i < WU_UGT1) { s = ug_w2;  o = i - WU_UG2;  cbits = 8; }
    else if (i < WU_UGT2) { s = ugt_w1; o = i - WU_UGT1; cbits = 8; }
    else if (i < WU_RG1)  { s = ugt_w2; o = i - WU_UGT2; cbits = 8; }
    else if (i < WU_RG2)  { s = rg_w1;  o = i - WU_RG1;  cbits = 8; }
    else if (i < WU_NS1)  { s = rg_w2;  o = i - WU_RG2;  cbits = 8; }
    else if (i < WU_NS2)  { s = ns_w1;  o = i - WU_NS1;  cbits = 8; }
    else if (i < WU_DK1)  { s = ns_w2;  o = i - WU_NS2;  cbits = 8; }
    else if (i < WU_DEC)  { s = dk_w1;  o = i - WU_DK1;  cbits = 8; }
    else                  { s = dec_w;  o = i - WU_DEC;  cbits = 7; }
    const int C  = 1 << cbits;
    const int kp = o >> cbits;
    const int c  = o & (C - 1);
    const float v0 = s[(2 * kp) * C + c];
    const float v1 = s[(2 * kp + 1) * C + c];
    const unsigned int h0 = __half_as_ushort(__float2half(v0));
    const unsigned int h1 = __half_as_ushort(__float2half(v1));
    ws[i] = h0 | (h1 << 16);
}

// Macro hygiene: no parameter named x/y/z/w (body does member access).
// acc.{x,y,z,w} are 4 adjacent output columns sharing one x half2.
#define DOT1(acc, wv, xv) { \
    acc.x = dot2f((wv).x, (xv), acc.x); acc.y = dot2f((wv).y, (xv), acc.y); \
    acc.z = dot2f((wv).z, (xv), acc.z); acc.w = dot2f((wv).w, (xv), acc.w); }

extern "C" __global__ void __launch_bounds__(1024, 4)
rnn_decay_kernel6(const float* __restrict__ data, const float* __restrict__ ts,
                  const float* __restrict__ ug_b1, const float* __restrict__ ug_b2,
                  const float* __restrict__ ugt_b1, const float* __restrict__ ugt_b2,
                  const float* __restrict__ rg_b1, const float* __restrict__ rg_b2,
                  const float* __restrict__ ns_b1, const float* __restrict__ ns_b2,
                  const float* __restrict__ dk_b1, const float* __restrict__ dk_w2,
                  const float* __restrict__ dk_b2, const float* __restrict__ dec_b,
                  const unsigned int* __restrict__ wsu, float* __restrict__ out)
{
    // 1024-thread / 16-wave variant of the verified column-split structure:
    // wave w owns output cols [16w,16w+16); lane owns 4 adjacent cols;
    // 16 kp-slices per wave (sl = lane>>2) reduced via shfl_xor 4/8/16/32.
    // Rationale: 4 waves/SIMD doubles in-flight loads (latency x MLP
    // equilibrium) without register-array prefetch (which spilled 3x).
    __shared__ __align__(16) unsigned int s_in_h[192];  // [ydec(128)|xh(64)] half2
    __shared__ __align__(16) unsigned int s_ns_h[192];  // [y*r (128)|xh(64)] half2
    __shared__ __align__(16) unsigned int s_y_h[128];   // y half2 (dk1 src)
    __shared__ __align__(16) unsigned int s_a_h[128];   // h / ns-h half2
    __shared__ __align__(16) unsigned int s_b_h[128];   // ht half2
    __shared__ __align__(16) unsigned int s_c_h[128];   // hr half2
    __shared__ __align__(16) unsigned int s_v_h[128];   // vol half2
    __shared__ __align__(16) float s_red[20];           // [0..3] mask, [4..19] dk

    const int tid  = threadIdx.x;
    const int w    = tid >> 6;                  // wave 0..15
    const int lane = tid & 63;
    const int c    = tid & 255;                 // only used when tid<256
    const int sl   = lane >> 2;                 // kp slice 0..15
    const int g    = lane & 3;                  // col group 0..3
    const int c0   = (w << 4) + (g << 2);       // first of 4 owned cols (0..252)
    const int h2b  = c0 >> 1;                   // half2-unit base for packs
    const int sld  = lane >> 1;                 // dec: kp slice 0..31
    const int c0d  = (w << 3) + ((lane & 1) << 2);  // dec: first of 4 cols (0..124)
    const int traj = blockIdx.x;

    const unsigned int* UG1  = wsu + WU_UG1;  const unsigned int* UG2  = wsu + WU_UG2;
    const unsigned int* UGT1 = wsu + WU_UGT1; const unsigned int* UGT2 = wsu + WU_UGT2;
    const unsigned int* RG1  = wsu + WU_RG1;  const unsigned int* RG2  = wsu + WU_RG2;
    const unsigned int* NS1  = wsu + WU_NS1;  const unsigned int* NS2  = wsu + WU_NS2;
    const unsigned int* DK1  = wsu + WU_DK1;  const unsigned int* DECW = wsu + WU_DEC;

    const float* dbase = data + (size_t)traj * NTP * (2 * INPUT);
    const float* tbase = ts + (size_t)traj * NTP;
    float* vol_out = out + OUT_VOL + (size_t)traj * NSTEPS * DEC_OUT;
    float* dts_out = out + OUT_DTS + (size_t)traj * NSTEPS;

    if (tid < 256)
        for (int t0 = c; t0 < NSTEPS; t0 += 256)
            dts_out[t0] = tbase[t0 + 1] - tbase[t0];

    const float dkb2s = dk_b2[0];

    float4 y4  = make_float4(0.f, 0.f, 0.f, 0.f);   // GRU state: owned cols
    float4 yt4 = y4;

    for (int t = -1; t < NSTEPS; ++t) {
        const bool first = (t < 0);

        // ================= phase X: x-stage + mask + dk1 dot =================
        float dt_t = 0.f;
        if (!first) dt_t = tbase[t + 1] - tbase[t];
        float xval = 0.f;
        if (tid < 256)
            xval = first ? dbase[c] : dbase[(size_t)(t + 1) * 256 + c];

        if (!first) {
            float4 aD = make_float4(0.f, 0.f, 0.f, 0.f);
            #pragma unroll 4
            for (int i = 0; i < 8; ++i) {
                const int kp = sl + (i << 4);
                const unsigned int xv = s_y_h[kp];
                const uint4 wv = *(const uint4*)(DK1 + (size_t)kp * 256 + c0);
                DOT1(aD, wv, xv);
            }
            aD = bfly4(aD, 4); aD = bfly4(aD, 8); aD = bfly4(aD, 16); aD = bfly4(aD, 32);
            const float4 dkb1v = *(const float4*)(dk_b1 + c0);
            const float4 dkw2v = *(const float4*)(dk_w2 + c0);
            float sdk = fmaxf(aD.x + dkb1v.x, 0.f) * dkw2v.x
                      + fmaxf(aD.y + dkb1v.y, 0.f) * dkw2v.y
                      + fmaxf(aD.z + dkb1v.z, 0.f) * dkw2v.z
                      + fmaxf(aD.w + dkb1v.w, 0.f) * dkw2v.w;
            sdk += __shfl_xor(sdk, 1, 64);
            sdk += __shfl_xor(sdk, 2, 64);
            if (lane == 0) s_red[4 + w] = sdk;          // w in 0..15
        }
        if (tid < 256) {
            float mv = (c >= 128) ? xval : 0.f;
            mv = wred(mv);
            if (lane == 0) s_red[w] = mv;               // w in 0..3 here
            if (c < 128) {
                const unsigned int px = packpair(xval);
                if (!(lane & 1)) { s_in_h[128 + (c >> 1)] = px; s_ns_h[128 + (c >> 1)] = px; }
            }
            if (first && !(lane & 1)) s_in_h[c >> 1] = 0u;   // ydec = 0
        }
        __syncthreads();                                               // A

        // ================= phase Y: decay scalar + ydec/vol pack =============
        const bool maskv = (s_red[0] + s_red[1] + s_red[2] + s_red[3]) > 0.f;
        float4 ydec4 = make_float4(0.f, 0.f, 0.f, 0.f);
        if (!first) {
            float dsum = dkb2s;
            #pragma unroll
            for (int i = 0; i < 16; ++i) dsum += s_red[4 + i];
            const float decay = fmaxf(dsum, 0.f);
            const float ef = __expf(-decay * dt_t);
            const float eh = __expf(-0.5f * decay * dt_t);
            float4 vol4;
            ydec4.x = yt4.x + (y4.x - yt4.x) * ef;
            ydec4.y = yt4.y + (y4.y - yt4.y) * ef;
            ydec4.z = yt4.z + (y4.z - yt4.z) * ef;
            ydec4.w = yt4.w + (y4.w - yt4.w) * ef;
            vol4.x = 0.5f * (y4.x + yt4.x + (y4.x - yt4.x) * eh);
            vol4.y = 0.5f * (y4.y + yt4.y + (y4.y - yt4.y) * eh);
            vol4.z = 0.5f * (y4.z + yt4.z + (y4.z - yt4.z) * eh);
            vol4.w = 0.5f * (y4.w + yt4.w + (y4.w - yt4.w) * eh);
            if (!sl) {
                uint2 pd; pd.x = pk2(ydec4.x, ydec4.y); pd.y = pk2(ydec4.z, ydec4.w);
                uint2 pv; pv.x = pk2(vol4.x, vol4.y);   pv.y = pk2(vol4.z, vol4.w);
                *(uint2*)(s_in_h + h2b) = pd;
                *(uint2*)(s_v_h + h2b)  = pv;
            }
        }
        __syncthreads();                                               // B

        // ================= phase G1: dec + ug1/ugt1/rg1 ======================
        if (!first) {
            float4 aE = make_float4(0.f, 0.f, 0.f, 0.f);
            #pragma unroll
            for (int i = 0; i < 4; ++i) {
                const int kp = sld + (i << 5);
                const unsigned int xv = s_v_h[kp];
                const uint4 wv = *(const uint4*)(DECW + (size_t)kp * 128 + c0d);
                DOT1(aE, wv, xv);
            }
            aE = bfly4(aE, 2); aE = bfly4(aE, 4); aE = bfly4(aE, 8);
            aE = bfly4(aE, 16); aE = bfly4(aE, 32);
            if (sld == 0) {
                const float4 decbv = *(const float4*)(dec_b + c0d);
                float4 o;
                o.x = aE.x + decbv.x; o.y = aE.y + decbv.y;
                o.z = aE.z + decbv.z; o.w = aE.w + decbv.w;
                *(float4*)(vol_out + (size_t)t * DEC_OUT + c0d) = o;
            }
        }
        {
            float4 aA = make_float4(0.f, 0.f, 0.f, 0.f), aB = aA, aC = aA;
            #pragma unroll 4
            for (int i = 0; i < 12; ++i) {
                const int kp = sl + (i << 4);
                const unsigned int xv = s_in_h[kp];
                const uint4 wa = *(const uint4*)(UG1  + (size_t)kp * 256 + c0);
                const uint4 wb = *(const uint4*)(UGT1 + (size_t)kp * 256 + c0);
                const uint4 wc = *(const uint4*)(RG1  + (size_t)kp * 256 + c0);
                DOT1(aA, wa, xv); DOT1(aB, wb, xv); DOT1(aC, wc, xv);
            }
            aA = bfly4(aA, 4); aA = bfly4(aA, 8); aA = bfly4(aA, 16); aA = bfly4(aA, 32);
            aB = bfly4(aB, 4); aB = bfly4(aB, 8); aB = bfly4(aB, 16); aB = bfly4(aB, 32);
            aC = bfly4(aC, 4); aC = bfly4(aC, 8); aC = bfly4(aC, 16); aC = bfly4(aC, 32);
            if (!sl) {
                const float4 ugb1v  = *(const float4*)(ug_b1  + c0);
                const float4 ugtb1v = *(const float4*)(ugt_b1 + c0);
                const float4 rgb1v  = *(const float4*)(rg_b1  + c0);
                uint2 pa, pb, pc;
                pa.x = pk2(fast_tanh(aA.x + ugb1v.x),  fast_tanh(aA.y + ugb1v.y));
                pa.y = pk2(fast_tanh(aA.z + ugb1v.z),  fast_tanh(aA.w + ugb1v.w));
                pb.x = pk2(fast_tanh(aB.x + ugtb1v.x), fast_tanh(aB.y + ugtb1v.y));
                pb.y = pk2(fast_tanh(aB.z + ugtb1v.z), fast_tanh(aB.w + ugtb1v.w));
                pc.x = pk2(fast_tanh(aC.x + rgb1v.x),  fast_tanh(aC.y + rgb1v.y));
                pc.y = pk2(fast_tanh(aC.z + rgb1v.z),  fast_tanh(aC.w + rgb1v.w));
                *(uint2*)(s_a_h + h2b) = pa;
                *(uint2*)(s_b_h + h2b) = pb;
                *(uint2*)(s_c_h + h2b) = pc;
            }
        }
        __syncthreads();                                               // C

        // ================= phase G2: ug2/ugt2/rg2 → u, ut, r =================
        float4 u4, ut4;
        {
            float4 aA = make_float4(0.f, 0.f, 0.f, 0.f), aB = aA, aC = aA;
            #pragma unroll 4
            for (int i = 0; i < 8; ++i) {
                const int kp = sl + (i << 4);
                const unsigned int xa = s_a_h[kp];
                const unsigned int xb = s_b_h[kp];
                const unsigned int xc = s_c_h[kp];
                const uint4 wa = *(const uint4*)(UG2  + (size_t)kp * 256 + c0);
                const uint4 wb = *(const uint4*)(UGT2 + (size_t)kp * 256 + c0);
                const uint4 wc = *(const uint4*)(RG2  + (size_t)kp * 256 + c0);
                DOT1(aA, wa, xa); DOT1(aB, wb, xb); DOT1(aC, wc, xc);
            }
            aA = bfly4(aA, 4); aA = bfly4(aA, 8); aA = bfly4(aA, 16); aA = bfly4(aA, 32);
            aB = bfly4(aB, 4); aB = bfly4(aB, 8); aB = bfly4(aB, 16); aB = bfly4(aB, 32);
            aC = bfly4(aC, 4); aC = bfly4(aC, 8); aC = bfly4(aC, 16); aC = bfly4(aC, 32);
            const float4 ugb2v  = *(const float4*)(ug_b2  + c0);
            const float4 ugtb2v = *(const float4*)(ugt_b2 + c0);
            const float4 rgb2v  = *(const float4*)(rg_b2  + c0);
            u4.x  = fast_sigmoid(aA.x + ugb2v.x);  u4.y  = fast_sigmoid(aA.y + ugb2v.y);
            u4.z  = fast_sigmoid(aA.z + ugb2v.z);  u4.w  = fast_sigmoid(aA.w + ugb2v.w);
            ut4.x = fast_sigmoid(aB.x + ugtb2v.x); ut4.y = fast_sigmoid(aB.y + ugtb2v.y);
            ut4.z = fast_sigmoid(aB.z + ugtb2v.z); ut4.w = fast_sigmoid(aB.w + ugtb2v.w);
            const float rx = fast_sigmoid(aC.x + rgb2v.x);
            const float ry = fast_sigmoid(aC.y + rgb2v.y);
            const float rz = fast_sigmoid(aC.z + rgb2v.z);
            const float rw = fast_sigmoid(aC.w + rgb2v.w);
            if (!sl) {
                uint2 pn;
                pn.x = pk2(ydec4.x * rx, ydec4.y * ry);
                pn.y = pk2(ydec4.z * rz, ydec4.w * rw);
                *(uint2*)(s_ns_h + h2b) = pn;      // first step: ydec=0 → 0 ✓
            }
        }
        __syncthreads();                                               // D

        // ================= phase N1: ns1 =====================================
        {
            float4 aA = make_float4(0.f, 0.f, 0.f, 0.f);
            #pragma unroll 4
            for (int i = 0; i < 12; ++i) {
                const int kp = sl + (i << 4);
                const unsigned int xv = s_ns_h[kp];
                const uint4 wa = *(const uint4*)(NS1 + (size_t)kp * 256 + c0);
                DOT1(aA, wa, xv);
            }
            aA = bfly4(aA, 4); aA = bfly4(aA, 8); aA = bfly4(aA, 16); aA = bfly4(aA, 32);
            if (!sl) {
                const float4 nsb1v = *(const float4*)(ns_b1 + c0);
                uint2 ph;
                ph.x = pk2(fast_tanh(aA.x + nsb1v.x), fast_tanh(aA.y + nsb1v.y));
                ph.y = pk2(fast_tanh(aA.z + nsb1v.z), fast_tanh(aA.w + nsb1v.w));
                *(uint2*)(s_a_h + h2b) = ph;       // reuse s_a_h (G2 done)
            }
        }
        __syncthreads();                                               // E

        // ================= phase N2: ns2 + state update ======================
        {
            float4 aA = make_float4(0.f, 0.f, 0.f, 0.f);
            #pragma unroll 4
            for (int i = 0; i < 8; ++i) {
                const int kp = sl + (i << 4);
                const unsigned int xv = s_a_h[kp];
                const uint4 wa = *(const uint4*)(NS2 + (size_t)kp * 256 + c0);
                DOT1(aA, wa, xv);
            }
            aA = bfly4(aA, 4); aA = bfly4(aA, 8); aA = bfly4(aA, 16); aA = bfly4(aA, 32);
            const float4 nsb2v = *(const float4*)(ns_b2 + c0);
            const float nx = aA.x + nsb2v.x, ny_ = aA.y + nsb2v.y;
            const float nz = aA.z + nsb2v.z, nw = aA.w + nsb2v.w;
            const float yx = (1.f - u4.x) * nx  + u4.x * ydec4.x;
            const float yy = (1.f - u4.y) * ny_ + u4.y * ydec4.y;
            const float yz = (1.f - u4.z) * nz  + u4.z * ydec4.z;
            const float yw = (1.f - u4.w) * nw  + u4.w * ydec4.w;
            const float tx = (1.f - ut4.x) * nx  + ut4.x * yt4.x;
            const float ty = (1.f - ut4.y) * ny_ + ut4.y * yt4.y;
            const float tz = (1.f - ut4.z) * nz  + ut4.z * yt4.z;
            const float tw = (1.f - ut4.w) * nw  + ut4.w * yt4.w;
            y4.x  = maskv ? yx : ydec4.x;  y4.y  = maskv ? yy : ydec4.y;
            y4.z  = maskv ? yz : ydec4.z;  y4.w  = maskv ? yw : ydec4.w;
            yt4.x = maskv ? tx : yt4.x;    yt4.y = maskv ? ty : yt4.y;
            yt4.z = maskv ? tz : yt4.z;    yt4.w = maskv ? tw : yt4.w;
            if (!sl) {
                uint2 py;
                py.x = pk2(y4.x, y4.y); py.y = pk2(y4.z, y4.w);
                *(uint2*)(s_y_h + h2b) = py;
            }
        }
        __syncthreads();                                               // F
    }

    if (!sl)
        *(float4*)(out + (size_t)traj * 256 + c0) = y4;
}

extern "C" void kernel_launch(void* const* d_in, const int* in_sizes, int n_in,
                              void* d_out, int out_size, void* d_ws, size_t ws_size,
                              hipStream_t stream) {
    const float* data   = (const float*)d_in[0];
    const float* ts     = (const float*)d_in[1];
    const float* ug_w1  = (const float*)d_in[2];
    const float* ug_b1  = (const float*)d_in[3];
    const float* ug_w2  = (const float*)d_in[4];
    const float* ug_b2  = (const float*)d_in[5];
    const float* ugt_w1 = (const float*)d_in[6];
    const float* ugt_b1 = (const float*)d_in[7];
    const float* ugt_w2 = (const float*)d_in[8];
    const float* ugt_b2 = (const float*)d_in[9];
    const float* rg_w1  = (const float*)d_in[10];
    const float* rg_b1  = (const float*)d_in[11];
    const float* rg_w2  = (const float*)d_in[12];
    const float* rg_b2  = (const float*)d_in[13];
    // d_in[14..17] = rgt_* : unused by the reference
    const float* ns_w1  = (const float*)d_in[18];
    const float* ns_b1  = (const float*)d_in[19];
    const float* ns_w2  = (const float*)d_in[20];
    const float* ns_b2  = (const float*)d_in[21];
    const float* dk_w1  = (const float*)d_in[22];
    const float* dk_b1  = (const float*)d_in[23];
    const float* dk_w2  = (const float*)d_in[24];
    const float* dk_b2  = (const float*)d_in[25];
    const float* dec_w  = (const float*)d_in[26];
    const float* dec_b  = (const float*)d_in[27];

    unsigned int* wsu = (unsigned int*)d_ws;

    convert_w<<<WU_TOT / 256, 256, 0, stream>>>(ug_w1, ug_w2, ugt_w1, ugt_w2,
                                                rg_w1, rg_w2, ns_w1, ns_w2,
                                                dk_w1, dec_w, wsu);

    rnn_decay_kernel6<<<NTRAJ, 1024, 0, stream>>>(
        data, ts, ug_b1, ug_b2, ugt_b1, ugt_b2, rg_b1, rg_b2, ns_b1, ns_b2,
        dk_b1, dk_w2, dk_b2, dec_b, wsu, (float*)d_out);
}

// Round 7
// 7624.426 us; speedup vs baseline: 6.3123x; 1.3285x over previous
//
#include <hip/hip_runtime.h>
#include <hip/hip_fp16.h>

#define NTRAJ   256
#define NTP     512
#define NSTEPS  511
#define LATENT  256
#define INPUT   128
#define DEC_OUT 128

#define OUT_VOL ((size_t)NTRAJ * LATENT)                              // 65536
#define OUT_DTS (OUT_VOL + (size_t)NTRAJ * NSTEPS * DEC_OUT)          // 16809984

// Pair-interleaved fp16 weight workspace (offsets in uint32 = half2 units).
// Layout per matrix [K][C]: ws[kp*C + c] = half2(W[2kp][c], W[2kp+1][c]).
#define WU_UG1  0
#define WU_UG2  49152
#define WU_UGT1 81920
#define WU_UGT2 131072
#define WU_RG1  163840
#define WU_RG2  212992
#define WU_NS1  245760
#define WU_NS2  294912
#define WU_DK1  327680
#define WU_DEC  360448
#define WU_TOT  376832

typedef _Float16 h2_t __attribute__((ext_vector_type(2)));
union U32H2 { unsigned int u; h2_t h; };

__device__ __forceinline__ float dot2f(unsigned int wu, unsigned int xu, float acc) {
#if defined(__has_builtin) && __has_builtin(__builtin_amdgcn_fdot2)
    U32H2 a, b; a.u = wu; b.u = xu;
    return __builtin_amdgcn_fdot2(a.h, b.h, acc, false);
#else
    U32H2 a, b; a.u = wu; b.u = xu;
    return acc + (float)a.h.x * (float)b.h.x + (float)a.h.y * (float)b.h.y;
#endif
}

__device__ __forceinline__ float wred(float v) {
    #pragma unroll
    for (int off = 32; off; off >>= 1) v += __shfl_down(v, off, 64);
    return v;
}
__device__ __forceinline__ float fast_sigmoid(float x) { return 1.0f / (1.0f + __expf(-x)); }
__device__ __forceinline__ float fast_tanh(float x) {
    float e = __expf(2.0f * x);
    return 1.0f - 2.0f / (e + 1.0f);
}
// Pack (v_even, v_odd) from adjacent lanes into one half2; only even lanes
// hold the correct result and write. Must be called by full waves.
__device__ __forceinline__ unsigned int packpair(float v) {
    float vn = __shfl_xor(v, 1, 64);
    U32H2 r; r.h.x = (_Float16)v; r.h.y = (_Float16)vn;
    return r.u;
}

// ---- weight prep: fp32 -> k-pair-interleaved half2 ----
extern "C" __global__ void __launch_bounds__(256)
convert_w(const float* __restrict__ ug_w1, const float* __restrict__ ug_w2,
          const float* __restrict__ ugt_w1, const float* __restrict__ ugt_w2,
          const float* __restrict__ rg_w1, const float* __restrict__ rg_w2,
          const float* __restrict__ ns_w1, const float* __restrict__ ns_w2,
          const float* __restrict__ dk_w1, const float* __restrict__ dec_w,
          unsigned int* __restrict__ ws)
{
    const int i = blockIdx.x * 256 + threadIdx.x;
    const float* s; int o; int cbits;
    if      (i < WU_UG2)  { s = ug_w1;  o = i;           cbits = 8; }
    else if (i < WU_UGT1) { s = ug_w2;  o = i - WU_UG2;  cbits = 8; }
    else if (i < WU_UGT2) { s = ugt_w1; o = i - WU_UGT1; cbits = 8; }
    else if (i < WU_RG1)  { s = ugt_w2; o = i - WU_UGT2; cbits = 8; }
    else if (i < WU_RG2)  { s = rg_w1;  o = i - WU_RG1;  cbits = 8; }
    else if (i < WU_NS1)  { s = rg_w2;  o = i - WU_RG2;  cbits = 8; }
    else if (i < WU_NS2)  { s = ns_w1;  o = i - WU_NS1;  cbits = 8; }
    else if (i < WU_DK1)  { s = ns_w2;  o = i - WU_NS2;  cbits = 8; }
    else if (i < WU_DEC)  { s = dk_w1;  o = i - WU_DK1;  cbits = 8; }
    else                  { s = dec_w;  o = i - WU_DEC;  cbits = 7; }
    const int C  = 1 << cbits;
    const int kp = o >> cbits;
    const int c  = o & (C - 1);
    const float v0 = s[(2 * kp) * C + c];
    const float v1 = s[(2 * kp + 1) * C + c];
    const unsigned int h0 = __half_as_ushort(__float2half(v0));
    const unsigned int h1 = __half_as_ushort(__float2half(v1));
    ws[i] = h0 | (h1 << 16);
}

// Macro hygiene: no parameter named x/y/z/w (body does member access).
#define DOT1(acc, wv, xv) { \
    acc.x = dot2f((wv).x, (xv), acc.x); acc.y = dot2f((wv).y, (xv), acc.y); \
    acc.z = dot2f((wv).z, (xv), acc.z); acc.w = dot2f((wv).w, (xv), acc.w); }

extern "C" __global__ void __launch_bounds__(1024, 4)
rnn_decay_kernel7(const float* __restrict__ data, const float* __restrict__ ts,
                  const float* __restrict__ ug_b1, const float* __restrict__ ug_b2,
                  const float* __restrict__ ugt_b1, const float* __restrict__ ugt_b2,
                  const float* __restrict__ rg_b1, const float* __restrict__ rg_b2,
                  const float* __restrict__ ns_b1, const float* __restrict__ ns_b2,
                  const float* __restrict__ dk_b1, const float* __restrict__ dk_w2,
                  const float* __restrict__ dk_b2, const float* __restrict__ dec_b,
                  const unsigned int* __restrict__ wsu, float* __restrict__ out)
{
    // R0's K-split structure (perfect 1KB-coalesced wave loads, LDS partials,
    // 11 barriers) scaled to 16 waves: each wave takes half the K-slice of R0.
    // Request size/line count per instruction UNCHANGED vs R0 (the R6 lesson:
    // never shrink segments below 128B) — only outstanding-load depth doubles.
    __shared__ __align__(16) float s_part[12288];       // 16 slots x 256 x 3 segs
    __shared__ __align__(16) float s_partd[4096];       // dec: 32 slots x 128
    __shared__ __align__(16) unsigned int s_in_h[192];  // [ydec(128)|xh(64)] half2
    __shared__ __align__(16) unsigned int s_ns_h[192];  // [y*r (128)|xh(64)] half2
    __shared__ __align__(16) unsigned int s_y_h[128];   // y half2 (dk1 src)
    __shared__ __align__(16) unsigned int s_a_h[128];   // h / ns-h half2
    __shared__ __align__(16) unsigned int s_b_h[128];   // ht half2
    __shared__ __align__(16) unsigned int s_c_h[128];   // hr half2
    __shared__ __align__(16) unsigned int s_v_h[128];   // vol half2
    __shared__ float s_ut[256];
    __shared__ float s_red[8];                          // [0..3] mask, [4..7] dk

    const int tid  = threadIdx.x;
    const int w    = tid >> 6;                  // wave 0..15
    const int lane = tid & 63;
    const int c    = tid & 255;
    const int cl4  = lane << 2;                 // 4 uint cols per lane (1KB/wave)
    const int traj = blockIdx.x;

    const unsigned int* UG1  = wsu + WU_UG1;  const unsigned int* UG2  = wsu + WU_UG2;
    const unsigned int* UGT1 = wsu + WU_UGT1; const unsigned int* UGT2 = wsu + WU_UGT2;
    const unsigned int* RG1  = wsu + WU_RG1;  const unsigned int* RG2  = wsu + WU_RG2;
    const unsigned int* NS1  = wsu + WU_NS1;  const unsigned int* NS2  = wsu + WU_NS2;
    const unsigned int* DK1  = wsu + WU_DK1;  const unsigned int* DECW = wsu + WU_DEC;

    const float* dbase = data + (size_t)traj * NTP * (2 * INPUT);
    const float* tbase = ts + (size_t)traj * NTP;
    float* vol_out = out + OUT_VOL + (size_t)traj * NSTEPS * DEC_OUT;
    float* dts_out = out + OUT_DTS + (size_t)traj * NSTEPS;

    if (tid < 256)
        for (int t0 = c; t0 < NSTEPS; t0 += 256)
            dts_out[t0] = tbase[t0 + 1] - tbase[t0];

    float r_y = 0.f, r_yt = 0.f;                // state held by tid<256

    const int kp12 = w * 12;                    // K=384 GEMVs: 12 kp per wave
    const int kp8  = w << 3;                    // K=256 GEMVs:  8 kp per wave

    for (int t = -1; t < NSTEPS; ++t) {
        const bool first = (t < 0);

        // ---- stage x, mask partials, xh pack ----
        if (tid < 256) {
            const float xval = first ? dbase[c] : dbase[(size_t)(t + 1) * 256 + c];
            float mv = (c >= 128) ? xval : 0.f;
            mv = wred(mv);
            if (lane == 0) s_red[w] = mv;               // w in 0..3 here
            if (c < 128) {
                const unsigned int px = packpair(xval);
                if (!(lane & 1)) { s_in_h[128 + (c >> 1)] = px; s_ns_h[128 + (c >> 1)] = px; }
            }
            if (first && !(lane & 1)) s_in_h[c >> 1] = 0u;   // ydec = 0
        }

        float r_ydec = 0.f, r_u = 0.f;
        bool maskv;

        if (!first) {
            // ---- dk1: y @ dk_w1, K=256, 8 kp per wave ----
            {
                float4 aD = make_float4(0.f, 0.f, 0.f, 0.f);
                #pragma unroll 4
                for (int i = 0; i < 8; ++i) {
                    const int kp = kp8 + i;
                    const unsigned int xv = s_y_h[kp];
                    const uint4 wv = *(const uint4*)(DK1 + (size_t)kp * 256 + cl4);
                    DOT1(aD, wv, xv);
                }
                *(float4*)(s_part + (w << 8) + cl4) = aD;
            }
            __syncthreads();                                           // B1
            if (tid < 256) {
                float v = dk_b1[c];
                #pragma unroll
                for (int i = 0; i < 16; ++i) v += s_part[(i << 8) + c];
                v = fmaxf(v, 0.f);
                const float pv = wred(v * dk_w2[c]);
                if (lane == 0) s_red[4 + w] = pv;
            }
            __syncthreads();                                           // B2
            maskv = (s_red[0] + s_red[1] + s_red[2] + s_red[3]) > 0.f;
            if (tid < 256) {
                const float decay = fmaxf(s_red[4] + s_red[5] + s_red[6] + s_red[7]
                                        + dk_b2[0], 0.f);
                const float dt = tbase[t + 1] - tbase[t];
                const float diff = r_y - r_yt;
                const float ef = __expf(-decay * dt);
                const float eh = __expf(-0.5f * decay * dt);
                r_ydec = r_yt + diff * ef;
                const float vol = 0.5f * (r_y + r_yt + diff * eh);
                const unsigned int pd  = packpair(r_ydec);
                const unsigned int pvv = packpair(vol);
                if (!(lane & 1)) { s_in_h[c >> 1] = pd; s_v_h[c >> 1] = pvv; }
            }
            __syncthreads();                                           // B3
        } else {
            __syncthreads();                                           // B3
            maskv = (s_red[0] + s_red[1] + s_red[2] + s_red[3]) > 0.f;
        }

        // ---- dec (K=256, src s_v_h; 8 rows per wave, 32 partial slots) ----
        if (!first) {
            float4 aE = make_float4(0.f, 0.f, 0.f, 0.f);
            const int hh = lane >> 5, cl = (lane & 31) << 2;
            const int kpb = kp8 + hh;
            #pragma unroll
            for (int i = 0; i < 4; ++i) {
                const int kp = kpb + (i << 1);
                const uint4 wv = *(const uint4*)(DECW + (size_t)kp * 128 + cl);
                const unsigned int xv = s_v_h[kp];
                DOT1(aE, wv, xv);
            }
            *(float4*)(s_partd + ((w << 1) + hh) * 128 + cl) = aE;
        }

        // ---- group1: ug1/ugt1/rg1 (K=384, 12 kp per wave, src s_in_h) ----
        {
            float4 aA = make_float4(0.f, 0.f, 0.f, 0.f), aB = aA, aC = aA;
            #pragma unroll 4
            for (int i = 0; i < 12; ++i) {
                const int kp = kp12 + i;
                const unsigned int xv = s_in_h[kp];
                const uint4 wa = *(const uint4*)(UG1  + (size_t)kp * 256 + cl4);
                const uint4 wb = *(const uint4*)(UGT1 + (size_t)kp * 256 + cl4);
                const uint4 wc = *(const uint4*)(RG1  + (size_t)kp * 256 + cl4);
                DOT1(aA, wa, xv); DOT1(aB, wb, xv); DOT1(aC, wc, xv);
            }
            *(float4*)(s_part + (w << 8) + cl4)          = aA;
            *(float4*)(s_part + 4096 + (w << 8) + cl4)   = aB;
            *(float4*)(s_part + 8192 + (w << 8) + cl4)   = aC;
        }
        __syncthreads();                                               // B4
        {   // 4-way parallel reduce: ug / ugt / rg / dec-out
            const int s = tid >> 8;
            if (s == 0) {
                float v = ug_b1[c];
                #pragma unroll
                for (int i = 0; i < 16; ++i) v += s_part[(i << 8) + c];
                v = fast_tanh(v);
                const unsigned int pk = packpair(v);
                if (!(lane & 1)) s_a_h[c >> 1] = pk;
            } else if (s == 1) {
                float v = ugt_b1[c];
                #pragma unroll
                for (int i = 0; i < 16; ++i) v += s_part[4096 + (i << 8) + c];
                v = fast_tanh(v);
                const unsigned int pk = packpair(v);
                if (!(lane & 1)) s_b_h[c >> 1] = pk;
            } else if (s == 2) {
                float v = rg_b1[c];
                #pragma unroll
                for (int i = 0; i < 16; ++i) v += s_part[8192 + (i << 8) + c];
                v = fast_tanh(v);
                const unsigned int pk = packpair(v);
                if (!(lane & 1)) s_c_h[c >> 1] = pk;
            } else if (!first && c < 128) {
                float vd = dec_b[c];
                #pragma unroll
                for (int i = 0; i < 32; ++i) vd += s_partd[(i << 7) + c];
                vol_out[(size_t)t * DEC_OUT + c] = vd;
            }
        }
        __syncthreads();                                               // B5

        // ---- group2: ug2/ugt2/rg2 (K=256, 8 kp per wave) ----
        {
            float4 aA = make_float4(0.f, 0.f, 0.f, 0.f), aB = aA, aC = aA;
            #pragma unroll 4
            for (int i = 0; i < 8; ++i) {
                const int kp = kp8 + i;
                const unsigned int xa = s_a_h[kp];
                const unsigned int xb = s_b_h[kp];
                const unsigned int xc = s_c_h[kp];
                const uint4 wa = *(const uint4*)(UG2  + (size_t)kp * 256 + cl4);
                const uint4 wb = *(const uint4*)(UGT2 + (size_t)kp * 256 + cl4);
                const uint4 wc = *(const uint4*)(RG2  + (size_t)kp * 256 + cl4);
                DOT1(aA, wa, xa); DOT1(aB, wb, xb); DOT1(aC, wc, xc);
            }
            *(float4*)(s_part + (w << 8) + cl4)          = aA;
            *(float4*)(s_part + 4096 + (w << 8) + cl4)   = aB;
            *(float4*)(s_part + 8192 + (w << 8) + cl4)   = aC;
        }
        __syncthreads();                                               // B6
        {
            const int s = tid >> 8;
            if (s == 0) {       // u and r (this thread holds r_ydec, does update)
                float v = ug_b2[c];
                #pragma unroll
                for (int i = 0; i < 16; ++i) v += s_part[(i << 8) + c];
                r_u = fast_sigmoid(v);
                float v2 = rg_b2[c];
                #pragma unroll
                for (int i = 0; i < 16; ++i) v2 += s_part[8192 + (i << 8) + c];
                const float rr = fast_sigmoid(v2);
                const unsigned int pk = packpair(r_ydec * rr);
                if (!(lane & 1)) s_ns_h[c >> 1] = pk;
            } else if (s == 1) { // ut
                float v = ugt_b2[c];
                #pragma unroll
                for (int i = 0; i < 16; ++i) v += s_part[4096 + (i << 8) + c];
                s_ut[c] = fast_sigmoid(v);
            }
        }
        __syncthreads();                                               // B7

        // ---- ns1 (K=384, 12 kp per wave, src s_ns_h) ----
        {
            float4 aA = make_float4(0.f, 0.f, 0.f, 0.f);
            #pragma unroll 4
            for (int i = 0; i < 12; ++i) {
                const int kp = kp12 + i;
                const unsigned int xv = s_ns_h[kp];
                const uint4 wa = *(const uint4*)(NS1 + (size_t)kp * 256 + cl4);
                DOT1(aA, wa, xv);
            }
            *(float4*)(s_part + (w << 8) + cl4) = aA;
        }
        __syncthreads();                                               // B8
        if (tid < 256) {
            float v = ns_b1[c];
            #pragma unroll
            for (int i = 0; i < 16; ++i) v += s_part[(i << 8) + c];
            v = fast_tanh(v);
            const unsigned int pk = packpair(v);
            if (!(lane & 1)) s_a_h[c >> 1] = pk;
        }
        __syncthreads();                                               // B9

        // ---- ns2 (K=256, 8 kp per wave, src s_a_h) + state update ----
        {
            float4 aA = make_float4(0.f, 0.f, 0.f, 0.f);
            #pragma unroll 4
            for (int i = 0; i < 8; ++i) {
                const int kp = kp8 + i;
                const unsigned int xv = s_a_h[kp];
                const uint4 wa = *(const uint4*)(NS2 + (size_t)kp * 256 + cl4);
                DOT1(aA, wa, xv);
            }
            *(float4*)(s_part + (w << 8) + cl4) = aA;
        }
        __syncthreads();                                               // B10
        if (tid < 256) {
            float nsv = ns_b2[c];
            #pragma unroll
            for (int i = 0; i < 16; ++i) nsv += s_part[(i << 8) + c];
            const float u = r_u, ut = s_ut[c];
            const float ny  = (1.f - u)  * nsv + u  * r_ydec;
            const float nyt = (1.f - ut) * nsv + ut * r_yt;
            r_y  = maskv ? ny  : r_ydec;
            r_yt = maskv ? nyt : r_yt;
            const unsigned int pk = packpair(r_y);
            if (!(lane & 1)) s_y_h[c >> 1] = pk;
        }
        __syncthreads();                                               // B11
    }

    if (tid < 256)
        out[(size_t)traj * 256 + c] = r_y;
}

extern "C" void kernel_launch(void* const* d_in, const int* in_sizes, int n_in,
                              void* d_out, int out_size, void* d_ws, size_t ws_size,
                              hipStream_t stream) {
    const float* data   = (const float*)d_in[0];
    const float* ts     = (const float*)d_in[1];
    const float* ug_w1  = (const float*)d_in[2];
    const float* ug_b1  = (const float*)d_in[3];
    const float* ug_w2  = (const float*)d_in[4];
    const float* ug_b2  = (const float*)d_in[5];
    const float* ugt_w1 = (const float*)d_in[6];
    const float* ugt_b1 = (const float*)d_in[7];
    const float* ugt_w2 = (const float*)d_in[8];
    const float* ugt_b2 = (const float*)d_in[9];
    const float* rg_w1  = (const float*)d_in[10];
    const float* rg_b1  = (const float*)d_in[11];
    const float* rg_w2  = (const float*)d_in[12];
    const float* rg_b2  = (const float*)d_in[13];
    // d_in[14..17] = rgt_* : unused by the reference
    const float* ns_w1  = (const float*)d_in[18];
    const float* ns_b1  = (const float*)d_in[19];
    const float* ns_w2  = (const float*)d_in[20];
    const float* ns_b2  = (const float*)d_in[21];
    const float* dk_w1  = (const float*)d_in[22];
    const float* dk_b1  = (const float*)d_in[23];
    const float* dk_w2  = (const float*)d_in[24];
    const float* dk_b2  = (const float*)d_in[25];
    const float* dec_w  = (const float*)d_in[26];
    const float* dec_b  = (const float*)d_in[27];

    unsigned int* wsu = (unsigned int*)d_ws;

    convert_w<<<WU_TOT / 256, 256, 0, stream>>>(ug_w1, ug_w2, ugt_w1, ugt_w2,
                                                rg_w1, rg_w2, ns_w1, ns_w2,
                                                dk_w1, dec_w, wsu);

    rnn_decay_kernel7<<<NTRAJ, 1024, 0, stream>>>(
        data, ts, ug_b1, ug_b2, ugt_b1, ugt_b2, rg_b1, rg_b2, ns_b1, ns_b2,
        dk_b1, dk_w2, dk_b2, dec_b, wsu, (float*)d_out);
}